// Round 24
// baseline (180.958 us; speedup 1.0000x reference)
//
#include <hip/hip_runtime.h>
#include <hip/hip_fp16.h>
#include <math.h>

#define NTOK 2048
#define HID  1024
#define FFN  2048
#define NEXP 8

#define BM 128
#define BN 128
#define BK 32
#define LDK 36            // Bsm col stride (hw) for conv-gemm1; 72B, b64-aligned
#define MAX_TILES 40
#define TLDA 66           // transpose LDS stride (hw): 33 dwords -> +1 bank/row
#define PREP_BLOCKS (NTOK/4)

// workspace layout (bytes); first 128 bytes zeroed each launch
#define WS_COUNTS 0      // 8 ints
#define WS_SEG    32     // 9 ints
#define WS_DONE   96     // 1 int (prep block-completion counter)
#define WS_PROBS  128                       // NTOK*NEXP floats
#define WS_LISTS  (128 + NTOK*NEXP*4)       // 8*NTOK ints
#define WS_XH     262144                    // [NTOK][HID] fp16 = 4MB
#define WS_W2T    (WS_XH + NTOK*HID*2)      // [E][HID][FFN] fp16 = 32MB
#define WS_HBUF   (WS_W2T + (size_t)NEXP*HID*FFN*2) // [5120][FFN] fp16 = 20MB

typedef _Float16 half8 __attribute__((ext_vector_type(8)));
typedef __fp16   fp16x2 __attribute__((ext_vector_type(2)));
typedef float    f32x4 __attribute__((ext_vector_type(4)));
typedef unsigned long long u64;

static __device__ __forceinline__ unsigned short f2h_bits(float f) {
  union { _Float16 h; unsigned short u; } v;
  v.h = (_Float16)f;
  return v.u;
}
static __device__ __forceinline__ unsigned pack2(float a, float b) {
  union { fp16x2 h; unsigned u; } v;
  v.h[0] = (__fp16)a; v.h[1] = (__fp16)b;
  return v.u;
}
static __device__ __forceinline__ unsigned cvt2(float a, float b) {
  union { fp16x2 h; unsigned u; } t;
  t.h = __builtin_amdgcn_cvt_pkrtz(a, b);   // v_cvt_pkrtz_f16_f32 (RTZ)
  return t.u;
}

#define GLOAD16(gsrc, ldst) \
  __builtin_amdgcn_global_load_lds( \
      (const __attribute__((address_space(1))) unsigned int*)(gsrc), \
      (__attribute__((address_space(3))) unsigned int*)(ldst), 16, 0, 0)

// Drain outstanding global_load_lds DMA (round-5 lesson: never rely on the
// compiler's vmcnt before s_barrier).
#define VMCNT0 asm volatile("s_waitcnt vmcnt(0)" ::: "memory")

// ---------------- pipelined 4-tile 64x64 transpose (fp32 -> fp16^T) ----------
// Verified in rounds 10/12/19/23.
template<int IS_W1>
static __device__ __forceinline__ void transpose4(
    int t0, const float* __restrict__ wsrc, unsigned short* __restrict__ wdst,
    unsigned short (*Ls)[64*TLDA], int tid)
{
  const int row = tid >> 2, cq = tid & 3;
  const int oc  = tid >> 2, rs = tid & 3;
  const int e = t0 >> 9;
  const int R = IS_W1 ? HID : FFN;
  const int C = IS_W1 ? FFN : HID;
  const float* src = wsrc + (size_t)e * HID * FFN;
  unsigned short* dst = wdst + (size_t)e * HID * FFN;
  float4 ld[2][4];

#define TGEOM(tt, r0v, c0v) \
    { const int rem_ = (t0 + (tt)) & 511; \
      r0v = IS_W1 ? ((rem_ >> 5) * 64) : ((rem_ >> 4) * 64); \
      c0v = IS_W1 ? ((rem_ & 31) * 64) : ((rem_ & 15) * 64); }

  {
    int r0, c0; TGEOM(0, r0, c0);
    const float4* sp = reinterpret_cast<const float4*>(
        src + (size_t)(r0 + row) * C + c0 + cq * 16);
#pragma unroll
    for (int j = 0; j < 4; ++j) ld[0][j] = sp[j];
  }
#pragma unroll
  for (int t = 0; t < 4; ++t) {
    if (t < 3) {
      int r0, c0; TGEOM(t + 1, r0, c0);
      const float4* sp = reinterpret_cast<const float4*>(
          src + (size_t)(r0 + row) * C + c0 + cq * 16);
#pragma unroll
      for (int j = 0; j < 4; ++j) ld[(t + 1) & 1][j] = sp[j];
    }
    {
      unsigned* Ld = reinterpret_cast<unsigned*>(Ls[t & 1]);
      const int dbase = row * (TLDA / 2) + cq * 8;
      const float4 a = ld[t & 1][0], b = ld[t & 1][1];
      const float4 c2 = ld[t & 1][2], d = ld[t & 1][3];
      Ld[dbase + 0] = pack2(a.x, a.y);  Ld[dbase + 1] = pack2(a.z, a.w);
      Ld[dbase + 2] = pack2(b.x, b.y);  Ld[dbase + 3] = pack2(b.z, b.w);
      Ld[dbase + 4] = pack2(c2.x, c2.y); Ld[dbase + 5] = pack2(c2.z, c2.w);
      Ld[dbase + 6] = pack2(d.x, d.y);  Ld[dbase + 7] = pack2(d.z, d.w);
    }
    __syncthreads();
    {
      int r0, c0; TGEOM(t, r0, c0);
      unsigned v[8];
#pragma unroll
      for (int j = 0; j < 8; ++j) {
        unsigned lo = Ls[t & 1][(rs * 16 + 2 * j    ) * TLDA + oc];
        unsigned hi = Ls[t & 1][(rs * 16 + 2 * j + 1) * TLDA + oc];
        v[j] = lo | (hi << 16);
      }
      unsigned short* dp = dst + (size_t)(c0 + oc) * R + r0 + rs * 16;
      *reinterpret_cast<uint4*>(dp)     = (uint4){v[0], v[1], v[2], v[3]};
      *reinterpret_cast<uint4*>(dp + 8) = (uint4){v[4], v[5], v[6], v[7]};
    }
  }
#undef TGEOM
}

// ---------------- prep: router + x->fp16; LAST block computes seg ------------
// seg is consumed only by the NEXT launch (stream-ordered kernel boundary =
// full fence), so no intra-launch gating is needed. counts are written and
// read exclusively via device-scope atomics (cross-XCD coherent).
__global__ __launch_bounds__(256) void moe_prep(
    const float* __restrict__ x, const float* __restrict__ rw,
    unsigned short* __restrict__ xh,
    int* __restrict__ counts, int* __restrict__ seg, int* __restrict__ done,
    int* __restrict__ lists, float* __restrict__ probs)
{
  const int tid = threadIdx.x;
  const int wid = tid >> 6, lane = tid & 63;
  const int t = blockIdx.x * 4 + wid;

  const float* xr = x + (size_t)t * HID + lane * 16;
  const float4* xp = reinterpret_cast<const float4*>(xr);
  float4 v0 = xp[0], v1 = xp[1], v2 = xp[2], v3 = xp[3];
  float xv[16] = {v0.x,v0.y,v0.z,v0.w, v1.x,v1.y,v1.z,v1.w,
                  v2.x,v2.y,v2.z,v2.w, v3.x,v3.y,v3.z,v3.w};
  float acc[NEXP];
#pragma unroll
  for (int e = 0; e < NEXP; ++e) acc[e] = 0.f;
#pragma unroll
  for (int j = 0; j < 16; ++j) {
    const float4* rp = reinterpret_cast<const float4*>(rw + (size_t)(lane*16 + j) * NEXP);
    float4 a = rp[0], b = rp[1];
    acc[0] += xv[j]*a.x; acc[1] += xv[j]*a.y; acc[2] += xv[j]*a.z; acc[3] += xv[j]*a.w;
    acc[4] += xv[j]*b.x; acc[5] += xv[j]*b.y; acc[6] += xv[j]*b.z; acc[7] += xv[j]*b.w;
  }
#pragma unroll
  for (int off = 32; off > 0; off >>= 1) {
#pragma unroll
    for (int e = 0; e < NEXP; ++e) acc[e] += __shfl_down(acc[e], off);
  }
  unsigned short* xd = xh + (size_t)t * HID + lane * 16;
  *reinterpret_cast<uint4*>(xd) =
      (uint4){pack2(v0.x,v0.y), pack2(v0.z,v0.w), pack2(v1.x,v1.y), pack2(v1.z,v1.w)};
  *reinterpret_cast<uint4*>(xd + 8) =
      (uint4){pack2(v2.x,v2.y), pack2(v2.z,v2.w), pack2(v3.x,v3.y), pack2(v3.z,v3.w)};
  if (lane == 0) {
    float m = acc[0];
#pragma unroll
    for (int e = 1; e < NEXP; ++e) m = fmaxf(m, acc[e]);
    float p[NEXP];
#pragma unroll
    for (int e = 0; e < NEXP; ++e) p[e] = expf(acc[e] - m);
    int i0 = 0;
#pragma unroll
    for (int e = 1; e < NEXP; ++e) if (p[e] > p[i0]) i0 = e;
    int i1 = -1;
#pragma unroll
    for (int e = 0; e < NEXP; ++e) {
      if (e == i0) continue;
      if (i1 < 0 || p[e] > p[i1]) i1 = e;
    }
    const float inv = 1.f / (p[i0] + p[i1]);
    probs[t * NEXP + i0] = p[i0] * inv;
    probs[t * NEXP + i1] = p[i1] * inv;
    int pos0 = atomicAdd(&counts[i0], 1); lists[i0 * NTOK + pos0] = t;
    int pos1 = atomicAdd(&counts[i1], 1); lists[i1 * NTOK + pos1] = t;
  }
  // block-completion: last block computes padded segment offsets
  __syncthreads();
  if (tid == 0) {
    __threadfence();                          // publish this block's atomics
    int old = atomicAdd(done, 1);
    if (old == PREP_BLOCKS - 1) {             // all counts final
      int run = 0;
#pragma unroll
      for (int e = 0; e < NEXP; ++e) {
        seg[e] = run;
        run += ((atomicAdd(&counts[e], 0) + BM - 1) / BM) * BM;
      }
      seg[NEXP] = run;                        // visible at kernel boundary
    }
  }
}

// ---------------- k2: GEMM1 (in-loop w1 conversion) | w2 transpose -----------
// bid [0,640):     gemm1 h = gelu(xh[tok] @ w1[e]) -> fp16 hbuf
// bid [640,1664):  w2 [E][FFN][HID] -> w2t [E][HID][FFN] fp16, 4 tiles/block
__global__ __launch_bounds__(256) void moe_k2(
    const unsigned short* __restrict__ xh, const float* __restrict__ w1,
    const float* __restrict__ w2, unsigned short* __restrict__ w2t,
    const int* __restrict__ counts, const int* __restrict__ seg,
    const int* __restrict__ lists, unsigned short* __restrict__ hbuf)
{
  __shared__ __align__(16) unsigned short SMEM[2*BM*BK + 2*128*LDK]; // 34KB
  __shared__ int tokL[BM];
  const int bid = blockIdx.x;
  const int tid = threadIdx.x;

  if (bid >= MAX_TILES * 16) {
    transpose4<0>((bid - MAX_TILES * 16) * 4, w2, w2t,
                  reinterpret_cast<unsigned short(*)[64 * TLDA]>(SMEM), tid);
    return;
  }

  const int tile = bid >> 4;
  const int jcol = bid & 15;            // FFN/128 = 16 col tiles
  const int rb = tile * BM;
  if (rb >= seg[NEXP]) return;
  int e = 0;
#pragma unroll
  for (int q = 1; q < NEXP; ++q) if (seg[q] <= rb) e = q;
  const int cnt = counts[e];
  const int rloc0 = rb - seg[e];

  unsigned short (*Asm)[BM*BK]   = reinterpret_cast<unsigned short(*)[BM*BK]>(SMEM);
  unsigned short (*Bsm)[128*LDK] = reinterpret_cast<unsigned short(*)[128*LDK]>(SMEM + 2*BM*BK);

  if (tid < BM) {
    int rl = rloc0 + tid;
    tokL[tid] = (rl < cnt) ? lists[e * NTOK + rl] : 0;
  }
  __syncthreads();

  const int lane = tid & 63;
  const int wid = tid >> 6;
  const int wr = (wid >> 1) * 64;
  const int wc = (wid & 1) * 64;
  const int lr = (lane >> 4) * 4;
  const int lc = lane & 15;
  const int khi = (lane >> 4) * 8;

  // A staging (DMA)
  const int cw8 = (lane & 3) * 8;
  const int r0 = wid*16 + (lane >> 2);
  const unsigned short* abase[2];
  abase[0] = xh + (size_t)tokL[r0]      * HID + cw8;
  abase[1] = xh + (size_t)tokL[64 + r0] * HID + cw8;

  // B staging: thread -> (kb, fb): k rows kb*4..+3, f cols fb*4..+3
  const int kb = tid >> 5;
  const int fb = tid & 31;
  const float* bbase = w1 + (size_t)e * HID * FFN + (size_t)jcol * 128 + fb * 4;

  f32x4 acc[4][4];
#pragma unroll
  for (int m = 0; m < 4; ++m)
#pragma unroll
    for (int n = 0; n < 4; ++n)
      acc[m][n] = (f32x4){0.f, 0.f, 0.f, 0.f};

  f32x4 bld[4];

#define LOADB1(kk) do { \
    _Pragma("unroll") \
    for (int j = 0; j < 4; ++j) \
      bld[j] = *reinterpret_cast<const f32x4*>(bbase + (size_t)((kk) + kb*4 + j) * FFN); \
  } while (0)

#define STAGEA1(buf, kk) do { \
    GLOAD16(abase[0] + (kk), &Asm[buf][(wid*64)*8]); \
    GLOAD16(abase[1] + (kk), &Asm[buf][(256 + wid*64)*8]); \
  } while (0)

#define CVTB1(buf) do { \
    _Pragma("unroll") \
    for (int i3 = 0; i3 < 4; ++i3) { \
      uint2 wv; \
      wv.x = cvt2(bld[0][i3], bld[1][i3]); \
      wv.y = cvt2(bld[2][i3], bld[3][i3]); \
      *reinterpret_cast<uint2*>(&Bsm[buf][(fb*4 + i3)*LDK + kb*4]) = wv; \
    } } while (0)

  LOADB1(0);
  STAGEA1(0, 0);
  int cur = 0;
  for (int kk = 0; kk < HID; kk += BK) {
    CVTB1(cur);
    VMCNT0;
    __syncthreads();
    if (kk + BK < HID) {
      LOADB1(kk + BK);
      STAGEA1(cur ^ 1, kk + BK);
    }
    half8 af[4], bf[4];
#pragma unroll
    for (int m = 0; m < 4; ++m)
      af[m] = *reinterpret_cast<const half8*>(&Asm[cur][(wr + m*16 + lc)*BK + khi]);
#pragma unroll
    for (int n = 0; n < 4; ++n) {
      union { u64 q[2]; half8 h; } t;
      const unsigned short* bp = &Bsm[cur][(wc + n*16 + lc)*LDK + khi];
      t.q[0] = *reinterpret_cast<const u64*>(bp);
      t.q[1] = *reinterpret_cast<const u64*>(bp + 4);
      bf[n] = t.h;
    }
#pragma unroll
    for (int m = 0; m < 4; ++m)
#pragma unroll
      for (int n = 0; n < 4; ++n)
        acc[m][n] = __builtin_amdgcn_mfma_f32_16x16x32_f16(af[m], bf[n], acc[m][n], 0, 0, 0);
    cur ^= 1;
  }
#undef LOADB1
#undef STAGEA1
#undef CVTB1

  // Unconditional: padding rows get deterministic values (token-0 data),
  // so gemm2 never reads poison from hbuf.
#pragma unroll
  for (int m = 0; m < 4; ++m) {
#pragma unroll
    for (int r = 0; r < 4; ++r) {
      unsigned short* hp = hbuf + (size_t)(rb + wr + m*16 + lr + r) * FFN + jcol*128 + wc + lc;
#pragma unroll
      for (int n = 0; n < 4; ++n) {
        float v = acc[m][n][r];
        float g = 0.5f * v * (1.f + erff(v * 0.70710678118f));   // exact erf-gelu
        hp[n*16] = f2h_bits(g);
      }
    }
  }
}

// ---------------- GEMM2: out[tok] += p * (hbuf @ w2t[e]^T), split-K x2 -------
// All-fp16 DMA structure (verified rounds 5/19/23).
__global__ __launch_bounds__(256) void moe_gemm2(
    const unsigned short* __restrict__ hbuf, const unsigned short* __restrict__ w2t,
    const int* __restrict__ counts, const int* __restrict__ seg,
    const int* __restrict__ lists, const float* __restrict__ probs,
    float* __restrict__ out)
{
  const int tile = blockIdx.x >> 4;
  const int jcol = (blockIdx.x >> 1) & 7;     // HID/128 = 8 col tiles
  const int ks   = blockIdx.x & 1;
  const int rb = tile * BM;
  if (rb >= seg[NEXP]) return;
  int e = 0;
#pragma unroll
  for (int q = 1; q < NEXP; ++q) if (seg[q] <= rb) e = q;
  const int cnt = counts[e];
  const int rloc0 = rb - seg[e];
  const int k0 = ks * (FFN / 2);
  const int k1 = k0 + (FFN / 2);

  __shared__ int tokL[BM];
  __shared__ float pL[BM];
  __shared__ __align__(16) unsigned short Asm[2][BM*BK];
  __shared__ __align__(16) unsigned short Bsm[2][BM*BK];

  const int tid = threadIdx.x;
  if (tid < BM) {
    int rl = rloc0 + tid;
    if (rl < cnt) {
      int tk = lists[e * NTOK + rl];
      tokL[tid] = tk;
      pL[tid] = probs[tk * NEXP + e];
    } else { tokL[tid] = 0; pL[tid] = 0.f; }
  }
  __syncthreads();

  const int lane = tid & 63;
  const int wid = tid >> 6;
  const int wr = (wid >> 1) * 64;
  const int wc = (wid & 1) * 64;
  const int lr = (lane >> 4) * 4;
  const int lc = lane & 15;
  const int khi = (lane >> 4) * 8;

  const int cw8 = (lane & 3) * 8;
  const int r0 = wid*16 + (lane >> 2);
  const unsigned short* abase[2];
  const unsigned short* bbase[2];
  abase[0] = hbuf + (size_t)(rb + r0)      * FFN + cw8;
  abase[1] = hbuf + (size_t)(rb + 64 + r0) * FFN + cw8;
  bbase[0] = w2t + ((size_t)e * HID + jcol*BN + r0)      * FFN + cw8;
  bbase[1] = w2t + ((size_t)e * HID + jcol*BN + 64 + r0) * FFN + cw8;

  f32x4 acc[4][4];
#pragma unroll
  for (int m = 0; m < 4; ++m)
#pragma unroll
    for (int n = 0; n < 4; ++n)
      acc[m][n] = (f32x4){0.f, 0.f, 0.f, 0.f};

#define STAGE2(buf, kk) do { \
    _Pragma("unroll") \
    for (int i = 0; i < 2; ++i) { \
      GLOAD16(abase[i] + (kk), &Asm[buf][(i*256 + wid*64)*8]); \
      GLOAD16(bbase[i] + (kk), &Bsm[buf][(i*256 + wid*64)*8]); \
    } } while (0)

  STAGE2(0, k0);
  VMCNT0;
  __syncthreads();
  int cur = 0;
  for (int kk = k0; kk < k1; kk += BK) {
    if (kk + BK < k1) STAGE2(cur ^ 1, kk + BK);
    half8 af[4], bf[4];
#pragma unroll
    for (int m = 0; m < 4; ++m)
      af[m] = *reinterpret_cast<const half8*>(&Asm[cur][(wr + m*16 + lc)*BK + khi]);
#pragma unroll
    for (int n = 0; n < 4; ++n)
      bf[n] = *reinterpret_cast<const half8*>(&Bsm[cur][(wc + n*16 + lc)*BK + khi]);
#pragma unroll
    for (int m = 0; m < 4; ++m)
#pragma unroll
      for (int n = 0; n < 4; ++n)
        acc[m][n] = __builtin_amdgcn_mfma_f32_16x16x32_f16(af[m], bf[n], acc[m][n], 0, 0, 0);
    VMCNT0;              // drain next-tile DMA issued above
    __syncthreads();
    cur ^= 1;
  }
#undef STAGE2

#pragma unroll
  for (int m = 0; m < 4; ++m) {
#pragma unroll
    for (int r = 0; r < 4; ++r) {
      const int lrow = wr + m*16 + lr + r;
      const int rl = rloc0 + lrow;
      if (rl >= cnt) continue;
      const int tok = tokL[lrow];
      const float p = pL[lrow];
      float* op = out + (size_t)tok * HID + jcol*BN + wc + lc;
#pragma unroll
      for (int n = 0; n < 4; ++n)
        atomicAdd(&op[n*16], p * acc[m][n][r]);   // <=4 commutative fp32 adds/element
    }
  }
}

extern "C" void kernel_launch(void* const* d_in, const int* in_sizes, int n_in,
                              void* d_out, int out_size, void* d_ws, size_t ws_size,
                              hipStream_t stream) {
  const float* x  = (const float*)d_in[0];
  const float* rw = (const float*)d_in[1];
  const float* w1 = (const float*)d_in[2];
  const float* w2 = (const float*)d_in[3];
  float* out = (float*)d_out;

  char* ws = (char*)d_ws;
  int*   counts = (int*)(ws + WS_COUNTS);
  int*   seg    = (int*)(ws + WS_SEG);
  int*   done   = (int*)(ws + WS_DONE);
  float* probs  = (float*)(ws + WS_PROBS);
  int*   lists  = (int*)(ws + WS_LISTS);
  unsigned short* xh   = (unsigned short*)(ws + WS_XH);
  unsigned short* w2t  = (unsigned short*)(ws + WS_W2T);
  unsigned short* hbuf = (unsigned short*)(ws + WS_HBUF);

  hipMemsetAsync(ws, 0, 128, stream);                                   // counts+seg+done
  hipMemsetAsync(d_out, 0, (size_t)NTOK * HID * sizeof(float), stream); // atomic target

  moe_prep<<<PREP_BLOCKS, 256, 0, stream>>>(x, rw, xh, counts, seg, done,
                                            lists, probs);
  moe_k2<<<MAX_TILES * 16 + 1024, 256, 0, stream>>>(xh, w1, w2, w2t,
                                                    counts, seg, lists, hbuf);
  moe_gemm2<<<MAX_TILES * 8 * 2, 256, 0, stream>>>(hbuf, w2t, counts, seg, lists, probs, out);
}

// Round 25
// 175.488 us; speedup vs baseline: 1.0312x; 1.0312x over previous
//
#include <hip/hip_runtime.h>
#include <hip/hip_fp16.h>
#include <math.h>

#define NTOK 2048
#define HID  1024
#define FFN  2048
#define NEXP 8

#define BM 128
#define BN 128
#define BK 32
#define LDK 36            // Bsm col stride (hw) for conv-gemm1; 72B, b64-aligned
#define MAX_TILES 40
#define TLDA 66           // transpose LDS stride (hw): 33 dwords -> +1 bank/row

// workspace layout (bytes)
#define WS_COUNTS 0
#define WS_SEG    32
#define WS_PROBS  128                       // NTOK*NEXP floats
#define WS_LISTS  (128 + NTOK*NEXP*4)       // 8*NTOK ints
#define WS_XH     262144                    // [NTOK][HID] fp16 = 4MB
#define WS_W2T    (WS_XH + NTOK*HID*2)      // [E][HID][FFN] fp16 = 32MB
#define WS_HBUF   (WS_W2T + (size_t)NEXP*HID*FFN*2) // [5120][FFN] fp16 = 20MB

typedef _Float16 half8 __attribute__((ext_vector_type(8)));
typedef __fp16   fp16x2 __attribute__((ext_vector_type(2)));
typedef float    f32x4 __attribute__((ext_vector_type(4)));
typedef unsigned long long u64;

static __device__ __forceinline__ unsigned short f2h_bits(float f) {
  union { _Float16 h; unsigned short u; } v;
  v.h = (_Float16)f;
  return v.u;
}
static __device__ __forceinline__ unsigned pack2(float a, float b) {
  union { fp16x2 h; unsigned u; } v;
  v.h[0] = (__fp16)a; v.h[1] = (__fp16)b;
  return v.u;
}
static __device__ __forceinline__ unsigned cvt2(float a, float b) {
  union { fp16x2 h; unsigned u; } t;
  t.h = __builtin_amdgcn_cvt_pkrtz(a, b);   // v_cvt_pkrtz_f16_f32 (RTZ)
  return t.u;
}

#define GLOAD16(gsrc, ldst) \
  __builtin_amdgcn_global_load_lds( \
      (const __attribute__((address_space(1))) unsigned int*)(gsrc), \
      (__attribute__((address_space(3))) unsigned int*)(ldst), 16, 0, 0)

// Drain outstanding global_load_lds DMA (round-5 lesson: never rely on the
// compiler's vmcnt before s_barrier).
#define VMCNT0 asm volatile("s_waitcnt vmcnt(0)" ::: "memory")

// ---------------- pipelined 4-tile 64x64 transpose (fp32 -> fp16^T) ----------
// Verified in rounds 10/12/19/23. 4 tiles/block, prefetch next tile before the
// LDS bounce, double-buffered LDS, one barrier per tile.
template<int IS_W1>
static __device__ __forceinline__ void transpose4(
    int t0, const float* __restrict__ wsrc, unsigned short* __restrict__ wdst,
    unsigned short (*Ls)[64*TLDA], int tid)
{
  const int row = tid >> 2, cq = tid & 3;
  const int oc  = tid >> 2, rs = tid & 3;
  const int e = t0 >> 9;
  const int R = IS_W1 ? HID : FFN;
  const int C = IS_W1 ? FFN : HID;
  const float* src = wsrc + (size_t)e * HID * FFN;
  unsigned short* dst = wdst + (size_t)e * HID * FFN;
  float4 ld[2][4];

#define TGEOM(tt, r0v, c0v) \
    { const int rem_ = (t0 + (tt)) & 511; \
      r0v = IS_W1 ? ((rem_ >> 5) * 64) : ((rem_ >> 4) * 64); \
      c0v = IS_W1 ? ((rem_ & 31) * 64) : ((rem_ & 15) * 64); }

  {
    int r0, c0; TGEOM(0, r0, c0);
    const float4* sp = reinterpret_cast<const float4*>(
        src + (size_t)(r0 + row) * C + c0 + cq * 16);
#pragma unroll
    for (int j = 0; j < 4; ++j) ld[0][j] = sp[j];
  }
#pragma unroll
  for (int t = 0; t < 4; ++t) {
    if (t < 3) {
      int r0, c0; TGEOM(t + 1, r0, c0);
      const float4* sp = reinterpret_cast<const float4*>(
          src + (size_t)(r0 + row) * C + c0 + cq * 16);
#pragma unroll
      for (int j = 0; j < 4; ++j) ld[(t + 1) & 1][j] = sp[j];
    }
    {
      unsigned* Ld = reinterpret_cast<unsigned*>(Ls[t & 1]);
      const int dbase = row * (TLDA / 2) + cq * 8;
      const float4 a = ld[t & 1][0], b = ld[t & 1][1];
      const float4 c2 = ld[t & 1][2], d = ld[t & 1][3];
      Ld[dbase + 0] = pack2(a.x, a.y);  Ld[dbase + 1] = pack2(a.z, a.w);
      Ld[dbase + 2] = pack2(b.x, b.y);  Ld[dbase + 3] = pack2(b.z, b.w);
      Ld[dbase + 4] = pack2(c2.x, c2.y); Ld[dbase + 5] = pack2(c2.z, c2.w);
      Ld[dbase + 6] = pack2(d.x, d.y);  Ld[dbase + 7] = pack2(d.z, d.w);
    }
    __syncthreads();
    {
      int r0, c0; TGEOM(t, r0, c0);
      unsigned v[8];
#pragma unroll
      for (int j = 0; j < 8; ++j) {
        unsigned lo = Ls[t & 1][(rs * 16 + 2 * j    ) * TLDA + oc];
        unsigned hi = Ls[t & 1][(rs * 16 + 2 * j + 1) * TLDA + oc];
        v[j] = lo | (hi << 16);
      }
      unsigned short* dp = dst + (size_t)(c0 + oc) * R + r0 + rs * 16;
      *reinterpret_cast<uint4*>(dp)     = (uint4){v[0], v[1], v[2], v[3]};
      *reinterpret_cast<uint4*>(dp + 8) = (uint4){v[4], v[5], v[6], v[7]};
    }
  }
#undef TGEOM
}

// ---------------- prep: router + x->fp16 (one wave per token) ----------------
__global__ __launch_bounds__(256) void moe_prep(
    const float* __restrict__ x, const float* __restrict__ rw,
    unsigned short* __restrict__ xh,
    int* __restrict__ counts, int* __restrict__ lists, float* __restrict__ probs)
{
  const int tid = threadIdx.x;
  const int wid = tid >> 6, lane = tid & 63;
  const int t = blockIdx.x * 4 + wid;

  const float* xr = x + (size_t)t * HID + lane * 16;
  const float4* xp = reinterpret_cast<const float4*>(xr);
  float4 v0 = xp[0], v1 = xp[1], v2 = xp[2], v3 = xp[3];
  float xv[16] = {v0.x,v0.y,v0.z,v0.w, v1.x,v1.y,v1.z,v1.w,
                  v2.x,v2.y,v2.z,v2.w, v3.x,v3.y,v3.z,v3.w};
  float acc[NEXP];
#pragma unroll
  for (int e = 0; e < NEXP; ++e) acc[e] = 0.f;
#pragma unroll
  for (int j = 0; j < 16; ++j) {
    const float4* rp = reinterpret_cast<const float4*>(rw + (size_t)(lane*16 + j) * NEXP);
    float4 a = rp[0], b = rp[1];
    acc[0] += xv[j]*a.x; acc[1] += xv[j]*a.y; acc[2] += xv[j]*a.z; acc[3] += xv[j]*a.w;
    acc[4] += xv[j]*b.x; acc[5] += xv[j]*b.y; acc[6] += xv[j]*b.z; acc[7] += xv[j]*b.w;
  }
#pragma unroll
  for (int off = 32; off > 0; off >>= 1) {
#pragma unroll
    for (int e = 0; e < NEXP; ++e) acc[e] += __shfl_down(acc[e], off);
  }
  unsigned short* xd = xh + (size_t)t * HID + lane * 16;
  *reinterpret_cast<uint4*>(xd) =
      (uint4){pack2(v0.x,v0.y), pack2(v0.z,v0.w), pack2(v1.x,v1.y), pack2(v1.z,v1.w)};
  *reinterpret_cast<uint4*>(xd + 8) =
      (uint4){pack2(v2.x,v2.y), pack2(v2.z,v2.w), pack2(v3.x,v3.y), pack2(v3.z,v3.w)};
  if (lane == 0) {
    float m = acc[0];
#pragma unroll
    for (int e = 1; e < NEXP; ++e) m = fmaxf(m, acc[e]);
    float p[NEXP];
#pragma unroll
    for (int e = 0; e < NEXP; ++e) p[e] = expf(acc[e] - m);
    int i0 = 0;
#pragma unroll
    for (int e = 1; e < NEXP; ++e) if (p[e] > p[i0]) i0 = e;
    int i1 = -1;
#pragma unroll
    for (int e = 0; e < NEXP; ++e) {
      if (e == i0) continue;
      if (i1 < 0 || p[e] > p[i1]) i1 = e;
    }
    const float inv = 1.f / (p[i0] + p[i1]);
    probs[t * NEXP + i0] = p[i0] * inv;
    probs[t * NEXP + i1] = p[i1] * inv;
    int pos0 = atomicAdd(&counts[i0], 1); lists[i0 * NTOK + pos0] = t;
    int pos1 = atomicAdd(&counts[i1], 1); lists[i1 * NTOK + pos1] = t;
  }
}

// ---------------- padded segment offsets ----------------
__global__ void moe_segoff(const int* __restrict__ counts, int* __restrict__ seg) {
  if (threadIdx.x == 0 && blockIdx.x == 0) {
    int run = 0;
    for (int e = 0; e < NEXP; ++e) {
      seg[e] = run;
      run += ((counts[e] + BM - 1) / BM) * BM;
    }
    seg[NEXP] = run;
  }
}

// ---------------- k2: GEMM1 (in-loop w1 conversion) | w2 transpose -----------
// bid [0,640):     gemm1 h = gelu(xh[tok] @ w1[e]) -> fp16 hbuf (round-15
//                  verified structure; no w1t dependency)
// bid [640,1664):  w2 [E][FFN][HID] -> w2t [E][HID][FFN] fp16, 4 tiles/block
//                  (round-12 verified; hides under gemm1's latency slack)
__global__ __launch_bounds__(256) void moe_k2(
    const unsigned short* __restrict__ xh, const float* __restrict__ w1,
    const float* __restrict__ w2, unsigned short* __restrict__ w2t,
    const int* __restrict__ counts, const int* __restrict__ seg,
    const int* __restrict__ lists, unsigned short* __restrict__ hbuf)
{
  __shared__ __align__(16) unsigned short SMEM[2*BM*BK + 2*128*LDK]; // 34KB
  __shared__ int tokL[BM];
  const int bid = blockIdx.x;
  const int tid = threadIdx.x;

  if (bid >= MAX_TILES * 16) {
    transpose4<0>((bid - MAX_TILES * 16) * 4, w2, w2t,
                  reinterpret_cast<unsigned short(*)[64 * TLDA]>(SMEM), tid);
    return;
  }

  const int tile = bid >> 4;
  const int jcol = bid & 15;            // FFN/128 = 16 col tiles
  const int rb = tile * BM;
  if (rb >= seg[NEXP]) return;
  int e = 0;
#pragma unroll
  for (int q = 1; q < NEXP; ++q) if (seg[q] <= rb) e = q;
  const int cnt = counts[e];
  const int rloc0 = rb - seg[e];

  unsigned short (*Asm)[BM*BK]   = reinterpret_cast<unsigned short(*)[BM*BK]>(SMEM);
  unsigned short (*Bsm)[128*LDK] = reinterpret_cast<unsigned short(*)[128*LDK]>(SMEM + 2*BM*BK);

  if (tid < BM) {
    int rl = rloc0 + tid;
    tokL[tid] = (rl < cnt) ? lists[e * NTOK + rl] : 0;
  }
  __syncthreads();

  const int lane = tid & 63;
  const int wid = tid >> 6;
  const int wr = (wid >> 1) * 64;
  const int wc = (wid & 1) * 64;
  const int lr = (lane >> 4) * 4;
  const int lc = lane & 15;
  const int khi = (lane >> 4) * 8;

  // A staging (DMA)
  const int cw8 = (lane & 3) * 8;
  const int r0 = wid*16 + (lane >> 2);
  const unsigned short* abase[2];
  abase[0] = xh + (size_t)tokL[r0]      * HID + cw8;
  abase[1] = xh + (size_t)tokL[64 + r0] * HID + cw8;

  // B staging: thread -> (kb, fb): k rows kb*4..+3, f cols fb*4..+3
  const int kb = tid >> 5;
  const int fb = tid & 31;
  const float* bbase = w1 + (size_t)e * HID * FFN + (size_t)jcol * 128 + fb * 4;

  f32x4 acc[4][4];
#pragma unroll
  for (int m = 0; m < 4; ++m)
#pragma unroll
    for (int n = 0; n < 4; ++n)
      acc[m][n] = (f32x4){0.f, 0.f, 0.f, 0.f};

  f32x4 bld[4];

#define LOADB1(kk) do { \
    _Pragma("unroll") \
    for (int j = 0; j < 4; ++j) \
      bld[j] = *reinterpret_cast<const f32x4*>(bbase + (size_t)((kk) + kb*4 + j) * FFN); \
  } while (0)

#define STAGEA1(buf, kk) do { \
    GLOAD16(abase[0] + (kk), &Asm[buf][(wid*64)*8]); \
    GLOAD16(abase[1] + (kk), &Asm[buf][(256 + wid*64)*8]); \
  } while (0)

#define CVTB1(buf) do { \
    _Pragma("unroll") \
    for (int i3 = 0; i3 < 4; ++i3) { \
      uint2 wv; \
      wv.x = cvt2(bld[0][i3], bld[1][i3]); \
      wv.y = cvt2(bld[2][i3], bld[3][i3]); \
      *reinterpret_cast<uint2*>(&Bsm[buf][(fb*4 + i3)*LDK + kb*4]) = wv; \
    } } while (0)

  LOADB1(0);
  STAGEA1(0, 0);
  int cur = 0;
  for (int kk = 0; kk < HID; kk += BK) {
    CVTB1(cur);
    VMCNT0;
    __syncthreads();
    if (kk + BK < HID) {
      LOADB1(kk + BK);
      STAGEA1(cur ^ 1, kk + BK);
    }
    half8 af[4], bf[4];
#pragma unroll
    for (int m = 0; m < 4; ++m)
      af[m] = *reinterpret_cast<const half8*>(&Asm[cur][(wr + m*16 + lc)*BK + khi]);
#pragma unroll
    for (int n = 0; n < 4; ++n) {
      union { u64 q[2]; half8 h; } t;
      const unsigned short* bp = &Bsm[cur][(wc + n*16 + lc)*LDK + khi];
      t.q[0] = *reinterpret_cast<const u64*>(bp);
      t.q[1] = *reinterpret_cast<const u64*>(bp + 4);
      bf[n] = t.h;
    }
#pragma unroll
    for (int m = 0; m < 4; ++m)
#pragma unroll
      for (int n = 0; n < 4; ++n)
        acc[m][n] = __builtin_amdgcn_mfma_f32_16x16x32_f16(af[m], bf[n], acc[m][n], 0, 0, 0);
    cur ^= 1;
  }
#undef LOADB1
#undef STAGEA1
#undef CVTB1

  // Unconditional: padding rows get deterministic values (token-0 data),
  // so gemm2 never reads poison from hbuf.
#pragma unroll
  for (int m = 0; m < 4; ++m) {
#pragma unroll
    for (int r = 0; r < 4; ++r) {
      unsigned short* hp = hbuf + (size_t)(rb + wr + m*16 + lr + r) * FFN + jcol*128 + wc + lc;
#pragma unroll
      for (int n = 0; n < 4; ++n) {
        float v = acc[m][n][r];
        float g = 0.5f * v * (1.f + erff(v * 0.70710678118f));   // exact erf-gelu
        hp[n*16] = f2h_bits(g);
      }
    }
  }
}

// ---------------- GEMM2: out[tok] += p * (hbuf @ w2t[e]^T), split-K x2 -------
// Round-5 verified all-fp16 DMA structure: both operands via global_load_lds.
__global__ __launch_bounds__(256) void moe_gemm2(
    const unsigned short* __restrict__ hbuf, const unsigned short* __restrict__ w2t,
    const int* __restrict__ counts, const int* __restrict__ seg,
    const int* __restrict__ lists, const float* __restrict__ probs,
    float* __restrict__ out)
{
  const int tile = blockIdx.x >> 4;
  const int jcol = (blockIdx.x >> 1) & 7;     // HID/128 = 8 col tiles
  const int ks   = blockIdx.x & 1;
  const int rb = tile * BM;
  if (rb >= seg[NEXP]) return;
  int e = 0;
#pragma unroll
  for (int q = 1; q < NEXP; ++q) if (seg[q] <= rb) e = q;
  const int cnt = counts[e];
  const int rloc0 = rb - seg[e];
  const int k0 = ks * (FFN / 2);
  const int k1 = k0 + (FFN / 2);

  __shared__ int tokL[BM];
  __shared__ float pL[BM];
  __shared__ __align__(16) unsigned short Asm[2][BM*BK];
  __shared__ __align__(16) unsigned short Bsm[2][BM*BK];

  const int tid = threadIdx.x;
  if (tid < BM) {
    int rl = rloc0 + tid;
    if (rl < cnt) {
      int tk = lists[e * NTOK + rl];
      tokL[tid] = tk;
      pL[tid] = probs[tk * NEXP + e];
    } else { tokL[tid] = 0; pL[tid] = 0.f; }
  }
  __syncthreads();

  const int lane = tid & 63;
  const int wid = tid >> 6;
  const int wr = (wid >> 1) * 64;
  const int wc = (wid & 1) * 64;
  const int lr = (lane >> 4) * 4;
  const int lc = lane & 15;
  const int khi = (lane >> 4) * 8;

  const int cw8 = (lane & 3) * 8;
  const int r0 = wid*16 + (lane >> 2);
  const unsigned short* abase[2];
  const unsigned short* bbase[2];
  abase[0] = hbuf + (size_t)(rb + r0)      * FFN + cw8;
  abase[1] = hbuf + (size_t)(rb + 64 + r0) * FFN + cw8;
  bbase[0] = w2t + ((size_t)e * HID + jcol*BN + r0)      * FFN + cw8;
  bbase[1] = w2t + ((size_t)e * HID + jcol*BN + 64 + r0) * FFN + cw8;

  f32x4 acc[4][4];
#pragma unroll
  for (int m = 0; m < 4; ++m)
#pragma unroll
    for (int n = 0; n < 4; ++n)
      acc[m][n] = (f32x4){0.f, 0.f, 0.f, 0.f};

#define STAGE2(buf, kk) do { \
    _Pragma("unroll") \
    for (int i = 0; i < 2; ++i) { \
      GLOAD16(abase[i] + (kk), &Asm[buf][(i*256 + wid*64)*8]); \
      GLOAD16(bbase[i] + (kk), &Bsm[buf][(i*256 + wid*64)*8]); \
    } } while (0)

  STAGE2(0, k0);
  VMCNT0;
  __syncthreads();
  int cur = 0;
  for (int kk = k0; kk < k1; kk += BK) {
    if (kk + BK < k1) STAGE2(cur ^ 1, kk + BK);
    half8 af[4], bf[4];
#pragma unroll
    for (int m = 0; m < 4; ++m)
      af[m] = *reinterpret_cast<const half8*>(&Asm[cur][(wr + m*16 + lc)*BK + khi]);
#pragma unroll
    for (int n = 0; n < 4; ++n)
      bf[n] = *reinterpret_cast<const half8*>(&Bsm[cur][(wc + n*16 + lc)*BK + khi]);
#pragma unroll
    for (int m = 0; m < 4; ++m)
#pragma unroll
      for (int n = 0; n < 4; ++n)
        acc[m][n] = __builtin_amdgcn_mfma_f32_16x16x32_f16(af[m], bf[n], acc[m][n], 0, 0, 0);
    VMCNT0;              // drain next-tile DMA issued above
    __syncthreads();
    cur ^= 1;
  }
#undef STAGE2

#pragma unroll
  for (int m = 0; m < 4; ++m) {
#pragma unroll
    for (int r = 0; r < 4; ++r) {
      const int lrow = wr + m*16 + lr + r;
      const int rl = rloc0 + lrow;
      if (rl >= cnt) continue;
      const int tok = tokL[lrow];
      const float p = pL[lrow];
      float* op = out + (size_t)tok * HID + jcol*BN + wc + lc;
#pragma unroll
      for (int n = 0; n < 4; ++n)
        atomicAdd(&op[n*16], p * acc[m][n][r]);   // <=4 commutative fp32 adds/element
    }
  }
}

extern "C" void kernel_launch(void* const* d_in, const int* in_sizes, int n_in,
                              void* d_out, int out_size, void* d_ws, size_t ws_size,
                              hipStream_t stream) {
  const float* x  = (const float*)d_in[0];
  const float* rw = (const float*)d_in[1];
  const float* w1 = (const float*)d_in[2];
  const float* w2 = (const float*)d_in[3];
  float* out = (float*)d_out;

  char* ws = (char*)d_ws;
  int*   counts = (int*)(ws + WS_COUNTS);
  int*   seg    = (int*)(ws + WS_SEG);
  float* probs  = (float*)(ws + WS_PROBS);
  int*   lists  = (int*)(ws + WS_LISTS);
  unsigned short* xh   = (unsigned short*)(ws + WS_XH);
  unsigned short* w2t  = (unsigned short*)(ws + WS_W2T);
  unsigned short* hbuf = (unsigned short*)(ws + WS_HBUF);

  hipMemsetAsync(ws, 0, 128, stream);                                   // counts+seg
  hipMemsetAsync(d_out, 0, (size_t)NTOK * HID * sizeof(float), stream); // atomic target

  moe_prep<<<NTOK/4, 256, 0, stream>>>(x, rw, xh, counts, lists, probs);
  moe_segoff<<<1, 64, 0, stream>>>(counts, seg);
  moe_k2<<<MAX_TILES * 16 + 1024, 256, 0, stream>>>(xh, w1, w2, w2t,
                                                    counts, seg, lists, hbuf);
  moe_gemm2<<<MAX_TILES * 8 * 2, 256, 0, stream>>>(hbuf, w2t, counts, seg, lists, probs, out);
}